// Round 2
// baseline (1051.471 us; speedup 1.0000x reference)
//
#include <hip/hip_runtime.h>

#define IN_F 4096
#define OUT_F 16384
#define MTOK 8192   // B*S = 4*2048

#define GBM 128
#define GBN 128
#define GBK 64

typedef __attribute__((ext_vector_type(4))) int   i32x4;
typedef __attribute__((ext_vector_type(4))) float f32x4;

__device__ __forceinline__ void gload_lds16(const void* g, void* lds) {
    __builtin_amdgcn_global_load_lds(
        (const __attribute__((address_space(1))) void*)g,
        (__attribute__((address_space(3))) void*)lds,
        16, 0, 0);
}

// ---------------------------------------------------------------------------
// Kernel 1: per-token absmax -> int8 quantize x, store scale
// ---------------------------------------------------------------------------
__global__ __launch_bounds__(256) void k_quant(const float* __restrict__ x,
                                               char* __restrict__ xq,
                                               float* __restrict__ xs) {
    const int m = blockIdx.x;
    const int t = threadIdx.x;
    const float* xrow = x + (size_t)m * IN_F;

    f32x4 v[4];
    float mx = 0.f;
#pragma unroll
    for (int i = 0; i < 4; ++i) {
        v[i] = *(const f32x4*)&xrow[(i * 256 + t) * 4];
        mx = fmaxf(mx, fmaxf(fmaxf(fabsf(v[i].x), fabsf(v[i].y)),
                             fmaxf(fabsf(v[i].z), fabsf(v[i].w))));
    }
#pragma unroll
    for (int off = 32; off > 0; off >>= 1)
        mx = fmaxf(mx, __shfl_xor(mx, off));

    __shared__ float wmax[4];
    const int wid = t >> 6;
    if ((t & 63) == 0) wmax[wid] = mx;
    __syncthreads();
    const float scale = fmaxf(fmaxf(fmaxf(wmax[0], wmax[1]),
                                    fmaxf(wmax[2], wmax[3])), 1e-5f);
    const float inv = 127.0f / scale;

    int* xqi = (int*)(xq + (size_t)m * IN_F);
#pragma unroll
    for (int i = 0; i < 4; ++i) {
        // rintf = round-half-even, matches jnp.round
        int q0 = (int)rintf(fminf(fmaxf(v[i].x * inv, -128.f), 127.f));
        int q1 = (int)rintf(fminf(fmaxf(v[i].y * inv, -128.f), 127.f));
        int q2 = (int)rintf(fminf(fmaxf(v[i].z * inv, -128.f), 127.f));
        int q3 = (int)rintf(fminf(fmaxf(v[i].w * inv, -128.f), 127.f));
        xqi[i * 256 + t] = (q0 & 255) | ((q1 & 255) << 8) |
                           ((q2 & 255) << 16) | (q3 << 24);
    }
    if (t == 0) xs[m] = scale;
}

// ---------------------------------------------------------------------------
// Kernel 2: ternary int32 weights -> int8 pack
// ---------------------------------------------------------------------------
__global__ __launch_bounds__(256) void k_wconv(const int* __restrict__ wt,
                                               int* __restrict__ w8) {
    const int total4 = OUT_F * IN_F / 4;
    int idx = blockIdx.x * 256 + threadIdx.x;
    const int stride = gridDim.x * 256;
    for (; idx < total4; idx += stride) {
        i32x4 w = *(const i32x4*)&wt[(size_t)idx * 4];
        w8[idx] = (w.x & 255) | ((w.y & 255) << 8) |
                  ((w.z & 255) << 16) | (w.w << 24);
    }
}

// ---------------------------------------------------------------------------
// Kernel 3: int8 GEMM with chunk-transposed LDS stripes (bank-conflict-free)
//
// LDS layout: each 16-row x 64B stripe (1024 B) stores logical
// (row r, kchunk q) at physical chunk index p = q*16 + r.  The MFMA
// fragment read for lane l wants (row l&15, kchunk l>>4) -> physical
// byte l*16 -> banks 4l..4l+3 mod 32 -> zero conflicts.
// global_load_lds writes linearly (base + lane*16), so the SOURCE address
// is permuted instead: staging lane p fetches global row (p&15),
// kchunk (p>>4)  [rule: both-sides-or-neither, m201 pattern].
// ---------------------------------------------------------------------------
__global__ __launch_bounds__(256, 2) void k_gemm(
    const char*  __restrict__ Aq,     // [MTOK][IN_F] int8
    const char*  __restrict__ Bq,     // [OUT_F][IN_F] int8
    const float* __restrict__ xs,     // [MTOK]
    const float* __restrict__ wsp,    // [1]
    float*       __restrict__ C) {    // [MTOK][OUT_F]
    __shared__ __align__(16) char sA[GBM * GBK];   // 8 KB = 8 stripes
    __shared__ __align__(16) char sB[GBN * GBK];   // 8 KB = 8 stripes

    const int t    = threadIdx.x;
    const int lane = t & 63;
    const int wid  = t >> 6;

    const int nTilesN = OUT_F / GBN;              // 128
    const int bm = blockIdx.x / nTilesN;
    const int bn = blockIdx.x % nTilesN;
    const int mBase = bm * GBM;
    const int nBase = bn * GBN;

    const int wm = (wid >> 1) * 64;               // wave tile origin in M
    const int wn = (wid & 1) * 64;                // wave tile origin in N

    // --- staging source (chunk-transposed): wave wid fills stripes wid and
    // wid+4; within a stripe, lane p fetches row (p&15), kchunk (p>>4).
    const int rr = lane & 15;
    const int kc = (lane >> 4) * 16;
    const char* Ag0 = Aq + (size_t)(mBase + wid * 16       + rr) * IN_F + kc;
    const char* Ag1 = Aq + (size_t)(mBase + (wid + 4) * 16 + rr) * IN_F + kc;
    const char* Bg0 = Bq + (size_t)(nBase + wid * 16       + rr) * IN_F + kc;
    const char* Bg1 = Bq + (size_t)(nBase + (wid + 4) * 16 + rr) * IN_F + kc;

    i32x4 acc[4][4];
#pragma unroll
    for (int i = 0; i < 4; ++i)
#pragma unroll
        for (int j = 0; j < 4; ++j)
            acc[i][j] = (i32x4){0, 0, 0, 0};

    // --- fragment read offsets: stripe (wm/16 + mi), physical byte lane*16
    const int aoff = (wm >> 4) * 1024 + lane * 16;  // + mi*1024
    const int boff = (wn >> 4) * 1024 + lane * 16;  // + ni*1024

    for (int k0 = 0; k0 < IN_F; k0 += GBK) {
        gload_lds16(Ag0 + k0, sA + wid * 1024);
        gload_lds16(Ag1 + k0, sA + 4096 + wid * 1024);
        gload_lds16(Bg0 + k0, sB + wid * 1024);
        gload_lds16(Bg1 + k0, sB + 4096 + wid * 1024);
        __syncthreads();   // compiler drains vmcnt before barrier

        i32x4 af[4], bf[4];
#pragma unroll
        for (int i = 0; i < 4; ++i)
            af[i] = *(const i32x4*)&sA[aoff + i * 1024];
#pragma unroll
        for (int i = 0; i < 4; ++i)
            bf[i] = *(const i32x4*)&sB[boff + i * 1024];

#pragma unroll
        for (int mi = 0; mi < 4; ++mi)
#pragma unroll
            for (int ni = 0; ni < 4; ++ni)
                acc[mi][ni] = __builtin_amdgcn_mfma_i32_16x16x64_i8(
                    af[mi], bf[ni], acc[mi][ni], 0, 0, 0);

        __syncthreads();   // protect LDS from next iteration's staging
    }

    // epilogue: D row = (lane>>4)*4 + r, col = lane&15
    const float wsc = wsp[0] * (1.0f / 127.0f);
    float rs[4][4];
#pragma unroll
    for (int mi = 0; mi < 4; ++mi)
#pragma unroll
        for (int r = 0; r < 4; ++r)
            rs[mi][r] = xs[mBase + wm + mi * 16 + (lane >> 4) * 4 + r] * wsc;

#pragma unroll
    for (int mi = 0; mi < 4; ++mi) {
#pragma unroll
        for (int ni = 0; ni < 4; ++ni) {
#pragma unroll
            for (int r = 0; r < 4; ++r) {
                const int row = mBase + wm + mi * 16 + (lane >> 4) * 4 + r;
                const int col = nBase + wn + ni * 16 + (lane & 15);
                C[(size_t)row * OUT_F + col] = (float)acc[mi][ni][r] * rs[mi][r];
            }
        }
    }
}

// ---------------------------------------------------------------------------
extern "C" void kernel_launch(void* const* d_in, const int* in_sizes, int n_in,
                              void* d_out, int out_size, void* d_ws, size_t ws_size,
                              hipStream_t stream) {
    const float* x   = (const float*)d_in[0];
    const int*   wt  = (const int*)d_in[1];
    const float* wsp = (const float*)d_in[2];
    float* out = (float*)d_out;

    char*  w8 = (char*)d_ws;
    char*  xq = (char*)d_ws + (size_t)OUT_F * IN_F;
    float* xs = (float*)((char*)d_ws + (size_t)OUT_F * IN_F
                                     + (size_t)MTOK * IN_F);

    k_wconv<<<8192, 256, 0, stream>>>(wt, (int*)w8);
    k_quant<<<MTOK, 256, 0, stream>>>(x, xq, xs);

    const int grid = (MTOK / GBM) * (OUT_F / GBN);
    k_gemm<<<grid, 256, 0, stream>>>(xq, w8, xs, wsp, out);
}

// Round 3
// 719.343 us; speedup vs baseline: 1.4617x; 1.4617x over previous
//
#include <hip/hip_runtime.h>

#define IN_F 4096
#define OUT_F 16384
#define MTOK 8192   // B*S

#define BM 256
#define BN 256
#define BK 64
#define NKT (IN_F / BK)   // 64 K-tiles

typedef __attribute__((ext_vector_type(4))) int   i32x4;
typedef __attribute__((ext_vector_type(4))) float f32x4;

__device__ __forceinline__ void gload_lds16(const void* g, void* lds) {
    __builtin_amdgcn_global_load_lds(
        (const __attribute__((address_space(1))) void*)g,
        (__attribute__((address_space(3))) void*)lds,
        16, 0, 0);
}

// ---------------------------------------------------------------------------
// Kernel 1: per-token absmax -> int8 quantize x, store scale
// ---------------------------------------------------------------------------
__global__ __launch_bounds__(256) void k_quant(const float* __restrict__ x,
                                               char* __restrict__ xq,
                                               float* __restrict__ xs) {
    const int m = blockIdx.x;
    const int t = threadIdx.x;
    const float* xrow = x + (size_t)m * IN_F;

    f32x4 v[4];
    float mx = 0.f;
#pragma unroll
    for (int i = 0; i < 4; ++i) {
        v[i] = *(const f32x4*)&xrow[(i * 256 + t) * 4];
        mx = fmaxf(mx, fmaxf(fmaxf(fabsf(v[i].x), fabsf(v[i].y)),
                             fmaxf(fabsf(v[i].z), fabsf(v[i].w))));
    }
#pragma unroll
    for (int off = 32; off > 0; off >>= 1)
        mx = fmaxf(mx, __shfl_xor(mx, off));

    __shared__ float wmax[4];
    const int wid = t >> 6;
    if ((t & 63) == 0) wmax[wid] = mx;
    __syncthreads();
    const float scale = fmaxf(fmaxf(fmaxf(wmax[0], wmax[1]),
                                    fmaxf(wmax[2], wmax[3])), 1e-5f);
    const float inv = 127.0f / scale;

    int* xqi = (int*)(xq + (size_t)m * IN_F);
#pragma unroll
    for (int i = 0; i < 4; ++i) {
        int q0 = (int)rintf(fminf(fmaxf(v[i].x * inv, -128.f), 127.f));
        int q1 = (int)rintf(fminf(fmaxf(v[i].y * inv, -128.f), 127.f));
        int q2 = (int)rintf(fminf(fmaxf(v[i].z * inv, -128.f), 127.f));
        int q3 = (int)rintf(fminf(fmaxf(v[i].w * inv, -128.f), 127.f));
        xqi[i * 256 + t] = (q0 & 255) | ((q1 & 255) << 8) |
                           ((q2 & 255) << 16) | (q3 << 24);
    }
    if (t == 0) xs[m] = scale;
}

// ---------------------------------------------------------------------------
// Kernel 2: ternary int32 weights -> int8 pack
// ---------------------------------------------------------------------------
__global__ __launch_bounds__(256) void k_wconv(const int* __restrict__ wt,
                                               int* __restrict__ w8) {
    const int total4 = OUT_F * IN_F / 4;
    int idx = blockIdx.x * 256 + threadIdx.x;
    const int stride = gridDim.x * 256;
    for (; idx < total4; idx += stride) {
        i32x4 w = *(const i32x4*)&wt[(size_t)idx * 4];
        w8[idx] = (w.x & 255) | ((w.y & 255) << 8) |
                  ((w.z & 255) << 16) | (w.w << 24);
    }
}

// ---------------------------------------------------------------------------
// Kernel 3: int8 GEMM — 256x256 tile, BK=64, 8 waves, triple-buffered LDS,
// counted vmcnt(4) pipeline (T3/T4), setprio (T5), XOR-swizzled LDS (T2),
// XCD-aware block swizzle (T1).
//
// LDS layout per buffer: A[256 rows][64B], row stored as 4x16B chunks with
// physical chunk c = q ^ ((row>>1)&3)  (q = logical k-chunk). Fragment
// ds_read_b128 per 8-lane group hits bank quads {0,16,4,20,8,24,12,28} ->
// conflict-free. Staging permutes the global SOURCE only within each row's
// 64B segment -> coalescing preserved (16x64B segments per wave-load).
//
// Pipeline: compute K-tile t from buf[t%3]; stage t+2 into buf[(t+2)%3]
// (== buf[(t-1)%3], reads done one barrier ago -> race-free). End of tile:
// s_waitcnt vmcnt(4)  (t+1 landed, t+2's 4 loads in flight) + s_barrier.
// ---------------------------------------------------------------------------
__global__ __launch_bounds__(512, 2) void k_gemm(
    const char*  __restrict__ Aq,     // [MTOK][IN_F] int8
    const char*  __restrict__ Bq,     // [OUT_F][IN_F] int8
    const float* __restrict__ xs,     // [MTOK]
    const float* __restrict__ wsp,    // [1]
    float*       __restrict__ C) {    // [MTOK][OUT_F]
    __shared__ __align__(16) char sA[3 * BM * BK];   // 48 KB
    __shared__ __align__(16) char sB[3 * BN * BK];   // 48 KB

    const int t    = threadIdx.x;
    const int lane = t & 63;
    const int wid  = t >> 6;
    const int wr   = wid >> 2;        // 0..1  (M)
    const int wc   = wid & 3;         // 0..3  (N)

    // T1: XCD swizzle; grid 2048 = 32(M) x 64(N), 2048 % 8 == 0
    const int bid = blockIdx.x;
    const int wg  = (bid & 7) * 256 + (bid >> 3);
    const int bm  = wg >> 6;
    const int bn  = wg & 63;
    const int mBase = bm * BM;
    const int nBase = bn * BN;

    // --- staging source offsets (per thread, 2 loads per operand) ---
    // chunk index P = j*512 + tid; row = P>>2, phys c = P&3,
    // logical q = c ^ ((row>>1)&3) = (P&3) ^ ((P>>3)&3)
    const int P0 = t, P1 = 512 + t;
    const size_t aSrc0 = (size_t)(mBase + (P0 >> 2)) * IN_F + (((P0 & 3) ^ ((P0 >> 3) & 3)) << 4);
    const size_t aSrc1 = (size_t)(mBase + (P1 >> 2)) * IN_F + (((P1 & 3) ^ ((P1 >> 3) & 3)) << 4);
    const size_t bSrc0 = (size_t)(nBase + (P0 >> 2)) * IN_F + (((P0 & 3) ^ ((P0 >> 3) & 3)) << 4);
    const size_t bSrc1 = (size_t)(nBase + (P1 >> 2)) * IN_F + (((P1 & 3) ^ ((P1 >> 3) & 3)) << 4);
    const int dstOff0 = wid * 1024;          // + d*16384
    const int dstOff1 = 8192 + wid * 1024;

    // --- fragment read bases (XOR-swizzled) ---
    const int swz = ((lane >> 4) ^ (((lane & 15) >> 1) & 3)) << 4;
    const int aFragBase = (wr * 128 + (lane & 15)) * BK + swz;  // + mi*1024 + d*16384
    const int bFragBase = (wc * 64  + (lane & 15)) * BK + swz;  // + ni*1024 + d*16384

    i32x4 acc[8][4];
#pragma unroll
    for (int i = 0; i < 8; ++i)
#pragma unroll
        for (int j = 0; j < 4; ++j)
            acc[i][j] = (i32x4){0, 0, 0, 0};

#define STAGE_A(kt, d)                                                        \
    {                                                                         \
        const size_t kOff = (size_t)(kt) * BK;                                \
        gload_lds16(Aq + aSrc0 + kOff, sA + (d) * 16384 + dstOff0);           \
        gload_lds16(Aq + aSrc1 + kOff, sA + (d) * 16384 + dstOff1);           \
    }
#define STAGE_B(kt, d)                                                        \
    {                                                                         \
        const size_t kOff = (size_t)(kt) * BK;                                \
        gload_lds16(Bq + bSrc0 + kOff, sB + (d) * 16384 + dstOff0);           \
        gload_lds16(Bq + bSrc1 + kOff, sB + (d) * 16384 + dstOff1);           \
    }

    // prologue: stage K-tiles 0 and 1; wait until tile 0 landed (4 in flight)
    STAGE_A(0, 0) STAGE_B(0, 0)
    STAGE_A(1, 1) STAGE_B(1, 1)
    asm volatile("s_waitcnt vmcnt(4)" ::: "memory");
    __builtin_amdgcn_s_barrier();

    int d = 0, d2 = 2;
    for (int kt = 0; kt < NKT; ++kt) {
        const int dOff = d * 16384;
        i32x4 aF[4], bF[4];

        // ---- phase 0: frags (mi 0-3, all ni) + stage A(kt+2) ----
#pragma unroll
        for (int i = 0; i < 4; ++i)
            aF[i] = *(const i32x4*)(sA + dOff + aFragBase + i * 1024);
#pragma unroll
        for (int i = 0; i < 4; ++i)
            bF[i] = *(const i32x4*)(sB + dOff + bFragBase + i * 1024);
        if (kt + 2 < NKT) STAGE_A(kt + 2, d2)
        __builtin_amdgcn_s_setprio(1);
#pragma unroll
        for (int mi = 0; mi < 4; ++mi)
#pragma unroll
            for (int ni = 0; ni < 4; ++ni)
                acc[mi][ni] = __builtin_amdgcn_mfma_i32_16x16x64_i8(
                    aF[mi], bF[ni], acc[mi][ni], 0, 0, 0);
        __builtin_amdgcn_s_setprio(0);

        // ---- phase 1: frags (mi 4-7) + stage B(kt+2) ----
#pragma unroll
        for (int i = 0; i < 4; ++i)
            aF[i] = *(const i32x4*)(sA + dOff + aFragBase + (4 + i) * 1024);
        if (kt + 2 < NKT) STAGE_B(kt + 2, d2)
        __builtin_amdgcn_s_setprio(1);
#pragma unroll
        for (int mi = 0; mi < 4; ++mi)
#pragma unroll
            for (int ni = 0; ni < 4; ++ni)
                acc[4 + mi][ni] = __builtin_amdgcn_mfma_i32_16x16x64_i8(
                    aF[mi], bF[ni], acc[4 + mi][ni], 0, 0, 0);
        __builtin_amdgcn_s_setprio(0);

        // ---- tile boundary: counted drain (never 0) + barrier ----
        asm volatile("s_waitcnt vmcnt(4)" ::: "memory");
        __builtin_amdgcn_s_barrier();

        d  = (d  == 2) ? 0 : d  + 1;
        d2 = (d2 == 2) ? 0 : d2 + 1;
    }

    // ---- epilogue ----
    const float wsc = wsp[0] * (1.0f / 127.0f);
#pragma unroll
    for (int mi = 0; mi < 8; ++mi) {
        float rs[4];
#pragma unroll
        for (int r = 0; r < 4; ++r)
            rs[r] = xs[mBase + wr * 128 + mi * 16 + (lane >> 4) * 4 + r] * wsc;
#pragma unroll
        for (int ni = 0; ni < 4; ++ni) {
            const int col = nBase + wc * 64 + ni * 16 + (lane & 15);
#pragma unroll
            for (int r = 0; r < 4; ++r) {
                const int row = mBase + wr * 128 + mi * 16 + (lane >> 4) * 4 + r;
                C[(size_t)row * OUT_F + col] = (float)acc[mi][ni][r] * rs[r];
            }
        }
    }
#undef STAGE_A
#undef STAGE_B
}

// ---------------------------------------------------------------------------
extern "C" void kernel_launch(void* const* d_in, const int* in_sizes, int n_in,
                              void* d_out, int out_size, void* d_ws, size_t ws_size,
                              hipStream_t stream) {
    const float* x   = (const float*)d_in[0];
    const int*   wt  = (const int*)d_in[1];
    const float* wsp = (const float*)d_in[2];
    float* out = (float*)d_out;

    char*  w8 = (char*)d_ws;
    char*  xq = (char*)d_ws + (size_t)OUT_F * IN_F;
    float* xs = (float*)((char*)d_ws + (size_t)OUT_F * IN_F
                                     + (size_t)MTOK * IN_F);

    k_wconv<<<8192, 256, 0, stream>>>(wt, (int*)w8);
    k_quant<<<MTOK, 256, 0, stream>>>(x, xq, xs);

    const int grid = (MTOK / BM) * (OUT_F / BN);  // 32 * 64 = 2048
    k_gemm<<<grid, 512, 0, stream>>>(xq, w8, xs, wsp, out);
}

// Round 4
// 577.607 us; speedup vs baseline: 1.8204x; 1.2454x over previous
//
#include <hip/hip_runtime.h>

#define IN_F 4096
#define OUT_F 16384
#define MTOK 8192   // B*S

#define BM 256
#define BN 256
#define BKB 128                 // K-bytes (=elements, i8) per K-tile
#define NKT (IN_F / BKB)        // 32 K-tiles
#define NIT (NKT / 2)           // 16 iterations, 2 K-tiles each

typedef __attribute__((ext_vector_type(4))) int   i32x4;
typedef __attribute__((ext_vector_type(4))) float f32x4;

__device__ __forceinline__ void gload_lds16(const void* g, void* l) {
    __builtin_amdgcn_global_load_lds(
        (const __attribute__((address_space(1))) void*)g,
        (__attribute__((address_space(3))) void*)l,
        16, 0, 0);
}

// ---------------------------------------------------------------------------
// Kernel 1: per-token absmax -> int8 quantize x, store scale
// ---------------------------------------------------------------------------
__global__ __launch_bounds__(256) void k_quant(const float* __restrict__ x,
                                               char* __restrict__ xq,
                                               float* __restrict__ xs) {
    const int m = blockIdx.x;
    const int t = threadIdx.x;
    const float* xrow = x + (size_t)m * IN_F;

    f32x4 v[4];
    float mx = 0.f;
#pragma unroll
    for (int i = 0; i < 4; ++i) {
        v[i] = *(const f32x4*)&xrow[(i * 256 + t) * 4];
        mx = fmaxf(mx, fmaxf(fmaxf(fabsf(v[i].x), fabsf(v[i].y)),
                             fmaxf(fabsf(v[i].z), fabsf(v[i].w))));
    }
#pragma unroll
    for (int off = 32; off > 0; off >>= 1)
        mx = fmaxf(mx, __shfl_xor(mx, off));

    __shared__ float wmax[4];
    const int wid = t >> 6;
    if ((t & 63) == 0) wmax[wid] = mx;
    __syncthreads();
    const float scale = fmaxf(fmaxf(fmaxf(wmax[0], wmax[1]),
                                    fmaxf(wmax[2], wmax[3])), 1e-5f);
    const float inv = 127.0f / scale;

    int* xqi = (int*)(xq + (size_t)m * IN_F);
#pragma unroll
    for (int i = 0; i < 4; ++i) {
        int q0 = (int)rintf(fminf(fmaxf(v[i].x * inv, -128.f), 127.f));
        int q1 = (int)rintf(fminf(fmaxf(v[i].y * inv, -128.f), 127.f));
        int q2 = (int)rintf(fminf(fmaxf(v[i].z * inv, -128.f), 127.f));
        int q3 = (int)rintf(fminf(fmaxf(v[i].w * inv, -128.f), 127.f));
        xqi[i * 256 + t] = (q0 & 255) | ((q1 & 255) << 8) |
                           ((q2 & 255) << 16) | (q3 << 24);
    }
    if (t == 0) xs[m] = scale;
}

// ---------------------------------------------------------------------------
// Kernel 2: ternary int32 weights -> int8 pack
// ---------------------------------------------------------------------------
__global__ __launch_bounds__(256) void k_wconv(const int* __restrict__ wt,
                                               int* __restrict__ w8) {
    const int total4 = OUT_F * IN_F / 4;
    int idx = blockIdx.x * 256 + threadIdx.x;
    const int stride = gridDim.x * 256;
    for (; idx < total4; idx += stride) {
        i32x4 w = *(const i32x4*)&wt[(size_t)idx * 4];
        w8[idx] = (w.x & 255) | ((w.y & 255) << 8) |
                  ((w.z & 255) << 16) | (w.w << 24);
    }
}

// ---------------------------------------------------------------------------
// Kernel 3: i8 GEMM — m201 8-phase template port.
// 256x256 tile, BK=128 i8, 8 waves (2Mx4N), per-wave 128x64.
// LDS 128KB: A[2buf][2half][128rows][128B] + B same (+64KB offset).
// Swizzle: phys_byte = row*128 + (col ^ ((row&7)<<4)) — fragment ds_read_b128
// spreads 64 lanes evenly over 8 bank-quads (conflict-free); staging permutes
// the global SOURCE within each row's 128B segment only (coalescing kept).
// Schedule per iter t (ktiles 2t in buf0 / 2t+1 in buf1):
//  ph1 rd A-lo+B-lo(buf0)  stage A1(2t+1)   MFMA q(lo,lo)
//  ph2 rd B-hi(buf0)       stage B0(2t+2)   MFMA q(lo,hi)
//  ph3 rd A-hi(buf0)       stage B1(2t+2)   MFMA q(hi,hi)
//  ph4 --                  stage A0(2t+2)   MFMA q(hi,lo)  vmcnt(6)
//  ph5 rd A-lo+B-lo(buf1)  stage A1(2t+2)   MFMA q(lo,lo)
//  ph6 rd B-hi(buf1)       stage B0(2t+3)   MFMA q(lo,hi)
//  ph7 rd A-hi(buf1)       stage B1(2t+3)   MFMA q(hi,hi)
//  ph8 --                  stage A0(2t+3)   MFMA q(hi,lo)  vmcnt(6)
// vmcnt(6) leaves 3 half-tiles in flight; retires exactly the K-tile read
// next. Last iter (no stages) uses vmcnt(0). Each phase: barrier before
// MFMA (after lgkmcnt(0)) and barrier after — lockstep role-split (T5).
// ---------------------------------------------------------------------------
__global__ __launch_bounds__(512, 2) void k_gemm(
    const char*  __restrict__ Aq,     // [MTOK][IN_F] int8
    const char*  __restrict__ Bq,     // [OUT_F][IN_F] int8
    const float* __restrict__ xs,     // [MTOK]
    const float* __restrict__ wsp,    // [1]
    float*       __restrict__ C) {    // [MTOK][OUT_F]
    __shared__ __align__(16) char lds[131072];   // A: 0..64K, B: 64K..128K

    const int t    = threadIdx.x;
    const int lane = t & 63;
    const int wid  = t >> 6;
    const int wr   = wid >> 2;        // 0..1  (M half)
    const int wc   = wid & 3;         // 0..3  (N quarter)

    // L2/L3-band grid mapping: XCD (bid&7) owns bn band of 8; bm sweeps slow.
    const int bid = blockIdx.x;
    const int bn  = (bid & 7) * 8 + ((bid >> 3) & 7);
    const int bm  = bid >> 6;
    const int mBase = bm * BM;
    const int nBase = bn * BN;

    // --- staging source geometry (per thread): physical chunk pc = j*512+t
    // row = pc>>3 (j=1 -> +64), src col-chunk = ((pc & 7) ^ (row & 7)) * 16
    const int r0 = t >> 3;
    const int c0 = ((t ^ r0) & 7) * 16;

#define STAGE_A(h, b, kt) do {                                                 \
        const size_t _s = (size_t)(mBase + (h) * 128 + r0) * IN_F + c0         \
                        + (size_t)(kt) * BKB;                                  \
        char* _d = lds + (b) * 32768 + (h) * 16384 + wid * 1024;               \
        gload_lds16(Aq + _s, _d);                                              \
        gload_lds16(Aq + _s + (size_t)64 * IN_F, _d + 8192);                   \
    } while (0)
#define STAGE_B(h, b, kt) do {                                                 \
        const size_t _s = (size_t)(nBase + (h) * 128 + r0) * IN_F + c0         \
                        + (size_t)(kt) * BKB;                                  \
        char* _d = lds + 65536 + (b) * 32768 + (h) * 16384 + wid * 1024;       \
        gload_lds16(Bq + _s, _d);                                              \
        gload_lds16(Bq + _s + (size_t)64 * IN_F, _d + 8192);                   \
    } while (0)

    // --- fragment read bases (swizzled). row&7 == lane&7 for all subtiles.
    const int slot  = (((lane >> 4) ^ (lane & 7)) << 4);
    const int aOff0 = (lane & 15) * 128 + slot;
    const int bOff0 = ((wc & 1) * 64 + (lane & 15)) * 128 + slot;
    const char* ldsA = lds + wr * 16384;                    // + buf*32768
    const char* ldsB = lds + 65536 + (wc >> 1) * 16384;     // + buf*32768

#define RD_A(dst, bOfs, miB)                                                   \
    _Pragma("unroll")                                                          \
    for (int mi = 0; mi < 4; ++mi) {                                           \
        dst[mi][0] = *(const i32x4*)(ldsA + (bOfs) + ((miB) + mi) * 2048 + aOff0);        \
        dst[mi][1] = *(const i32x4*)(ldsA + (bOfs) + ((miB) + mi) * 2048 + (aOff0 ^ 64)); \
    }
#define RD_B(dst, bOfs, niB)                                                   \
    _Pragma("unroll")                                                          \
    for (int ni = 0; ni < 2; ++ni) {                                           \
        dst[ni][0] = *(const i32x4*)(ldsB + (bOfs) + ((niB) + ni) * 2048 + bOff0);        \
        dst[ni][1] = *(const i32x4*)(ldsB + (bOfs) + ((niB) + ni) * 2048 + (bOff0 ^ 64)); \
    }
#define MFMA_Q(A, MIB, B, NIB)                                                 \
    __builtin_amdgcn_s_setprio(1);                                             \
    _Pragma("unroll")                                                          \
    for (int mi = 0; mi < 4; ++mi)                                             \
        _Pragma("unroll")                                                      \
        for (int ni = 0; ni < 2; ++ni)                                         \
            _Pragma("unroll")                                                  \
            for (int kk = 0; kk < 2; ++kk)                                     \
                acc[(MIB) + mi][(NIB) + ni] =                                  \
                    __builtin_amdgcn_mfma_i32_16x16x64_i8(                     \
                        A[mi][kk], B[ni][kk], acc[(MIB) + mi][(NIB) + ni],     \
                        0, 0, 0);                                              \
    __builtin_amdgcn_s_setprio(0);
#define BAR()   __builtin_amdgcn_s_barrier()
#define LGKM0() asm volatile("s_waitcnt lgkmcnt(0)" ::: "memory")
#define VM6()   asm volatile("s_waitcnt vmcnt(6)" ::: "memory")
#define VM0()   asm volatile("s_waitcnt vmcnt(0)" ::: "memory")

    i32x4 acc[8][4];
#pragma unroll
    for (int i = 0; i < 8; ++i)
#pragma unroll
        for (int j = 0; j < 4; ++j)
            acc[i][j] = (i32x4){0, 0, 0, 0};

    i32x4 aLo[4][2], aHi[4][2], bLo[2][2], bHi[2][2];

    // ---- prologue: K0 fully + K1 {B0,B1,A0}; leave K1's 3 halves in flight
    STAGE_A(0, 0, 0); STAGE_A(1, 0, 0); STAGE_B(0, 0, 0); STAGE_B(1, 0, 0);
    STAGE_B(0, 1, 1); STAGE_B(1, 1, 1); STAGE_A(0, 1, 1);
    VM6();
    BAR();

    for (int it = 0; it < NIT; ++it) {
        const int kt1 = 2 * it + 1;
        const int kn0 = 2 * it + 2;
        const int kn1 = 2 * it + 3;
        const bool more = (it < NIT - 1);

        // ---- ph1
        RD_A(aLo, 0, 0); RD_B(bLo, 0, 0);
        STAGE_A(1, 1, kt1);
        BAR(); LGKM0();
        MFMA_Q(aLo, 0, bLo, 0);
        BAR();
        // ---- ph2
        RD_B(bHi, 0, 2);
        if (more) STAGE_B(0, 0, kn0);
        BAR(); LGKM0();
        MFMA_Q(aLo, 0, bHi, 2);
        BAR();
        // ---- ph3
        RD_A(aHi, 0, 4);
        if (more) STAGE_B(1, 0, kn0);
        BAR(); LGKM0();
        MFMA_Q(aHi, 4, bHi, 2);
        BAR();
        // ---- ph4
        if (more) STAGE_A(0, 0, kn0);
        BAR();
        MFMA_Q(aHi, 4, bLo, 0);
        if (more) { VM6(); } else { VM0(); }
        BAR();
        // ---- ph5
        RD_A(aLo, 32768, 0); RD_B(bLo, 32768, 0);
        if (more) STAGE_A(1, 0, kn0);
        BAR(); LGKM0();
        MFMA_Q(aLo, 0, bLo, 0);
        BAR();
        // ---- ph6
        RD_B(bHi, 32768, 2);
        if (more) STAGE_B(0, 1, kn1);
        BAR(); LGKM0();
        MFMA_Q(aLo, 0, bHi, 2);
        BAR();
        // ---- ph7
        RD_A(aHi, 32768, 4);
        if (more) STAGE_B(1, 1, kn1);
        BAR(); LGKM0();
        MFMA_Q(aHi, 4, bHi, 2);
        BAR();
        // ---- ph8
        if (more) STAGE_A(0, 1, kn1);
        BAR();
        MFMA_Q(aHi, 4, bLo, 0);
        if (more) { VM6(); } else { VM0(); }
        BAR();
    }

    // ---- epilogue: D row = (lane>>4)*4 + r, col = lane&15 (R1/R3-verified)
    const float wsc = wsp[0] * (1.0f / 127.0f);
#pragma unroll
    for (int mi = 0; mi < 8; ++mi) {
        float rs[4];
#pragma unroll
        for (int r = 0; r < 4; ++r)
            rs[r] = xs[mBase + wr * 128 + mi * 16 + (lane >> 4) * 4 + r] * wsc;
#pragma unroll
        for (int ni = 0; ni < 4; ++ni) {
            const int col = nBase + wc * 64 + ni * 16 + (lane & 15);
#pragma unroll
            for (int r = 0; r < 4; ++r) {
                const int row = mBase + wr * 128 + mi * 16 + (lane >> 4) * 4 + r;
                C[(size_t)row * OUT_F + col] = (float)acc[mi][ni][r] * rs[r];
            }
        }
    }
}

// ---------------------------------------------------------------------------
extern "C" void kernel_launch(void* const* d_in, const int* in_sizes, int n_in,
                              void* d_out, int out_size, void* d_ws, size_t ws_size,
                              hipStream_t stream) {
    const float* x   = (const float*)d_in[0];
    const int*   wt  = (const int*)d_in[1];
    const float* wsp = (const float*)d_in[2];
    float* out = (float*)d_out;

    char*  w8 = (char*)d_ws;
    char*  xq = (char*)d_ws + (size_t)OUT_F * IN_F;
    float* xs = (float*)((char*)d_ws + (size_t)OUT_F * IN_F
                                     + (size_t)MTOK * IN_F);

    k_wconv<<<8192, 256, 0, stream>>>(wt, (int*)w8);
    k_quant<<<MTOK, 256, 0, stream>>>(x, xq, xs);

    const int grid = (MTOK / BM) * (OUT_F / BN);  // 32 * 64 = 2048
    k_gemm<<<grid, 512, 0, stream>>>(xq, w8, xs, wsp, out);
}